// Round 1
// 272.709 us; speedup vs baseline: 1.0765x; 1.0765x over previous
//
#include <hip/hip_runtime.h>

// ---- problem dims (fixed by setup_inputs) ----
#define N_NODES 131072
#define DIM     128
#define NG      2048
#define HD      512

typedef unsigned short u16;
typedef _Float16 half8 __attribute__((ext_vector_type(8)));
typedef short  short8 __attribute__((ext_vector_type(8)));
typedef float  f32x4  __attribute__((ext_vector_type(4)));

// ---- static device scratch (referenced ONLY from device code) ----
__device__ u16   g_fb[(size_t)N_NODES * DIM];     // features fp16 (33.5 MB)
__device__ u16   g_wm[(size_t)HD * DIM];          // W_m fp16 (rows j, cols d)
__device__ u16   g_wg[(size_t)2048 * 1024];       // [Wih[:,:H]+Whh | Wih[:,H:]] fp16
__device__ float g_w2[(size_t)NG * DIM];          // w2 = h @ W_m, fp32 (1 MB)
__device__ u16   g_sp[(size_t)NG * DIM];          // S' = sum a_n f_n, fp16
__device__ float g_tp[NG];                        // t' = sum a_n
__device__ float g_gates[(size_t)NG * 2048];      // 16.8 MB
__device__ u16   g_Acat[(size_t)NG * 1024];       // [h | r] fp16, 4 MB
__device__ float g_c[(size_t)NG * HD];
__device__ int   g_start[NG + 1];
__device__ int   g_isbf16;
__device__ int   g_idx64;

__device__ __forceinline__ float bf2f(u16 u) {
  unsigned v = ((unsigned)u) << 16;
  float f; __builtin_memcpy(&f, &v, 4); return f;
}
__device__ __forceinline__ u16 f2bf(float f) {
  unsigned u; __builtin_memcpy(&u, &f, 4);
  u += 0x7FFFu + ((u >> 16) & 1u);
  return (u16)(u >> 16);
}
__device__ __forceinline__ u16 f2h(float f) {
  _Float16 h = (_Float16)f; u16 u; __builtin_memcpy(&u, &h, 2); return u;
}
__device__ __forceinline__ float rdf(const void* p, int i) {
  return g_isbf16 ? bf2f(((const u16*)p)[i]) : ((const float*)p)[i];
}

#define GLD16(gp, lp) __builtin_amdgcn_global_load_lds(                          \
    (const __attribute__((address_space(1))) void*)(gp),                         \
    (__attribute__((address_space(3))) void*)(lp), 16, 0, 0)

// ---- dtype detection ----
__global__ void k_detect(const void* feat, const void* gi) {
  __shared__ int cnt;
  if (threadIdx.x == 0) cnt = 0;
  __syncthreads();
  u16 u = ((const u16*)feat)[threadIdx.x];
  float v = bf2f(u);
  float a = fabsf(v);
  int ok = (v == v) && a >= 1e-6f && a <= 1e6f;
  atomicAdd(&cnt, ok);
  __syncthreads();
  if (threadIdx.x == 0) {
    g_isbf16 = (cnt >= 230);
    g_idx64 = (((const int*)gi)[N_NODES - 1] == 0);
  }
}

// ---- conversions (pair-indexed): features->fp16, W_m->fp16, Wg ----
#define NFP ((size_t)N_NODES * DIM / 2)
#define NWP ((size_t)HD * DIM / 2)
#define NWG ((size_t)2048 * 1024 / 2)
__global__ __launch_bounds__(256) void k_cvt_all(const void* f, const void* wm,
                                                 const void* wih, const void* whh) {
  const int isb = g_isbf16;
  size_t i = (size_t)blockIdx.x * 256 + threadIdx.x;
  if (i < NFP + NWP) {
    const void* src = (i < NFP) ? f : wm;
    u16* dst = (i < NFP) ? g_fb : g_wm;
    size_t off = (i < NFP) ? i : i - NFP;
    float v0, v1;
    if (isb) {
      unsigned pr = ((const unsigned*)src)[off];
      v0 = bf2f((u16)pr); v1 = bf2f((u16)(pr >> 16));
    } else {
      float2 v = ((const float2*)src)[off];
      v0 = v.x; v1 = v.y;
    }
    ((unsigned*)dst)[off] = (unsigned)f2h(v0) | ((unsigned)f2h(v1) << 16);
  } else if (i < NFP + NWP + NWG) {
    size_t off = i - NFP - NWP;
    int n = (int)(off >> 9), kp = (int)(off & 511);
    int k = kp * 2;
    float v0 = rdf(wih, n * 1024 + k);
    float v1 = rdf(wih, n * 1024 + k + 1);
    if (k < 512) {
      v0 += rdf(whh, n * 512 + k);
      v1 += rdf(whh, n * 512 + k + 1);
    }
    ((unsigned*)g_wg)[off] = (unsigned)f2h(v0) | ((unsigned)f2h(v1) << 16);
  }
}
#define CVT_BLOCKS ((int)((NFP + NWP + NWG + 255) / 256))

// ---- per-graph start offsets from sorted graph_index ----
__global__ void k_offsets(const void* giv) {
  int n = blockIdx.x * 256 + threadIdx.x;
  if (n >= N_NODES) return;
  const int idx64 = g_idx64;
  int g = idx64 ? (int)((const long long*)giv)[n] : ((const int*)giv)[n];
  if (n == 0) {
    for (int x = 0; x <= g; ++x) g_start[x] = 0;
  } else {
    int gp = idx64 ? (int)((const long long*)giv)[n - 1] : ((const int*)giv)[n - 1];
    for (int x = gp + 1; x <= g; ++x) g_start[x] = n;
  }
  if (n == N_NODES - 1) {
    for (int x = g + 1; x <= NG; ++x) g_start[x] = N_NODES;
  }
}

// ---- GEMM: gates = [h|r] @ Wg^T  (M=2048,N=2048,K=1024), 64x64 tiles,
// two K-tiles per barrier (double LDS buffer). Launched only for loop>=1. ----
__global__ __launch_bounds__(256) void k_gemm_gates() {
  __shared__ u16 As[2][64 * 64];                     // 2x8 KB, XOR-swizzled
  __shared__ u16 Bs[2][64 * 64];
  const int t = threadIdx.x, lid = t & 63, w = t >> 6;
  const int m0 = blockIdx.x * 64, n0 = blockIdx.y * 64;
  const int rr = lid & 15, quad = lid >> 4;
  const int rsub = lid >> 3;                         // 0..7
  const int cs = (lid & 7) ^ rsub;                   // swizzled k-chunk
  const int wm = (w >> 1) * 32, wn = (w & 1) * 32;
  f32x4 acc[2][2] = {};
  for (int kt2 = 0; kt2 < 8; ++kt2) {
#pragma unroll
    for (int b = 0; b < 2; ++b) {
      const int k0 = (kt2 * 2 + b) * 64;
      GLD16(g_Acat + (size_t)(m0 + w * 16 + rsub) * 1024 + k0 + cs * 8, As[b] + (w * 16) * 64);
      GLD16(g_Acat + (size_t)(m0 + w * 16 + 8 + rsub) * 1024 + k0 + cs * 8, As[b] + (w * 16 + 8) * 64);
      GLD16(g_wg   + (size_t)(n0 + w * 16 + rsub) * 1024 + k0 + cs * 8, Bs[b] + (w * 16) * 64);
      GLD16(g_wg   + (size_t)(n0 + w * 16 + 8 + rsub) * 1024 + k0 + cs * 8, Bs[b] + (w * 16 + 8) * 64);
    }
    __syncthreads();
#pragma unroll
    for (int b = 0; b < 2; ++b)
#pragma unroll
      for (int kk = 0; kk < 2; ++kk) {
        const int qb = kk * 4 + quad;
        const int sw = (qb ^ (rr & 7)) << 3;
        half8 af[2], bfr[2];
#pragma unroll
        for (int i = 0; i < 2; ++i) af[i]  = *(const half8*)(As[b] + (wm + i * 16 + rr) * 64 + sw);
#pragma unroll
        for (int j = 0; j < 2; ++j) bfr[j] = *(const half8*)(Bs[b] + (wn + j * 16 + rr) * 64 + sw);
#pragma unroll
        for (int i = 0; i < 2; ++i)
#pragma unroll
          for (int j = 0; j < 2; ++j)
            acc[i][j] = __builtin_amdgcn_mfma_f32_16x16x32_f16(bfr[j], af[i], acc[i][j], 0, 0, 0);
      }
    __syncthreads();
  }
#pragma unroll
  for (int i = 0; i < 2; ++i)
#pragma unroll
    for (int j = 0; j < 2; ++j) {
      const int row = m0 + wm + i * 16 + rr;
      const int c0 = n0 + wn + j * 16 + quad * 4;
      *(f32x4*)(g_gates + (size_t)row * 2048 + c0) = acc[i][j];
    }
}

// ---- LSTM cell elementwise + fused w2 = h @ W_m.
// One block = 4 graphs (256 threads, 8 (g,j) elements each). Grid NG/4 = 512.
// first=1: gates are pure bias (loop 0, q_star = h = 0) and c_prev = 0, so the
// gates GEMM is skipped entirely for loop 0 and g_c is never read stale. ----
__global__ __launch_bounds__(256) void k_lstm(const void* __restrict__ b_ih,
                                              const void* __restrict__ b_hh,
                                              void* __restrict__ out,
                                              int wout, int first) {
  __shared__ float s_hf[4][512];                    // h fp32 for w2 phase (8 KB)
  __shared__ float s_red[4][4][128];                // per-wave w2 partials (8 KB)
  const int t = threadIdx.x;
  const int g0 = blockIdx.x * 4;
#pragma unroll
  for (int k = 0; k < 8; ++k) {
    const int idx = k * 256 + t;
    const int gg = idx >> 9, j = idx & 511;
    const int g = g0 + gg;
    float xi = rdf(b_ih, j)        + rdf(b_hh, j);
    float xf = rdf(b_ih, j + 512)  + rdf(b_hh, j + 512);
    float xg = rdf(b_ih, j + 1024) + rdf(b_hh, j + 1024);
    float xo = rdf(b_ih, j + 1536) + rdf(b_hh, j + 1536);
    float cp = 0.f;
    if (!first) {
      const float* grow = g_gates + (size_t)g * 2048;
      xi += grow[j];
      xf += grow[j + 512];
      xg += grow[j + 1024];
      xo += grow[j + 1536];
      cp = g_c[(size_t)g * 512 + j];
    }
    float si = 1.f / (1.f + __expf(-xi));
    float sf = 1.f / (1.f + __expf(-xf));
    float tg = tanhf(xg);
    float so = 1.f / (1.f + __expf(-xo));
    float cn = sf * cp + si * tg;
    float hn = so * tanhf(cn);
    g_c[(size_t)g * 512 + j] = cn;
    g_Acat[(size_t)g * 1024 + j] = f2h(hn);
    s_hf[gg][j] = hn;
    if (wout) {
      if (g_isbf16) ((u16*)out)[(size_t)g * 1024 + j] = f2bf(hn);
      else          ((float*)out)[(size_t)g * 1024 + j] = hn;
    }
  }
  __syncthreads();
  // --- w2[g][d] = sum_j h[g][j] * W_m[j][d] for the block's 4 graphs ---
  // thread t: dg = t&15 owns 8 d's (d0 = dg*8); jg = t>>4 owns 32 j's.
  // W_m (128 KB fp16, L2-resident) is read once per block -> 64 MB L2 total.
  const int dg = t & 15, jg = t >> 4;
  float acc[4][8] = {};
  for (int jj = 0; jj < 32; ++jj) {
    const int j = jg * 32 + jj;
    half8 wv = *(const half8*)(g_wm + (size_t)j * 128 + dg * 8);
    float wf[8];
#pragma unroll
    for (int d = 0; d < 8; ++d) wf[d] = (float)wv[d];
#pragma unroll
    for (int g = 0; g < 4; ++g) {
      const float hv = s_hf[g][j];                  // 16-lane LDS broadcast
#pragma unroll
      for (int d = 0; d < 8; ++d) acc[g][d] += hv * wf[d];
    }
  }
  // reduce over jg. lane = (jg&3)*16 + dg -> shfl_xor 16/32 sums jg&3 in-wave.
#pragma unroll
  for (int g = 0; g < 4; ++g)
#pragma unroll
    for (int d = 0; d < 8; ++d) {
      acc[g][d] += __shfl_xor(acc[g][d], 16, 64);
      acc[g][d] += __shfl_xor(acc[g][d], 32, 64);
    }
  const int w = t >> 6;
  if ((t & 63) < 16) {
#pragma unroll
    for (int g = 0; g < 4; ++g) {
      *(f32x4*)&s_red[w][g][dg * 8]     = *(f32x4*)&acc[g][0];
      *(f32x4*)&s_red[w][g][dg * 8 + 4] = *(f32x4*)&acc[g][4];
    }
  }
  __syncthreads();
  {
    const int g = t >> 6, d2 = (t & 63) * 2;        // 4 graphs x 128 d / 256 thr
#pragma unroll
    for (int p = 0; p < 2; ++p) {
      const int d = d2 + p;
      g_w2[(size_t)(g0 + g) * 128 + d] =
          s_red[0][g][d] + s_red[1][g][d] + s_red[2][g][d] + s_red[3][g][d];
    }
  }
}

// ---- attention scores+softmax+weighted feature sum. One block per graph.
// Writes S' = sum(a_n f_n) fp16 [NG x 128] and t' = sum(a_n) fp32 [NG].
__global__ __launch_bounds__(256) void k_attn_s() {
  const int g = blockIdx.x;
  const int t = threadIdx.x, lid = t & 63, wid = t >> 6;
  const int c = lid & 15;                            // 8-col chunk index
  const int slot = lid >> 4;                         // node slot 0..3
  __shared__ float s_m[4], s_l[4];
  __shared__ float s_s[4][DIM];
  const int s = g_start[g], e = g_start[g + 1];
  float w2r[8];
  *(float4*)(w2r)     = *(const float4*)(g_w2 + (size_t)g * DIM + c * 8);
  *(float4*)(w2r + 4) = *(const float4*)(g_w2 + (size_t)g * DIM + c * 8 + 4);
  float mrun = -3.0e38f, lsum = 0.f;
  float racc[8] = {0.f, 0.f, 0.f, 0.f, 0.f, 0.f, 0.f, 0.f};
  for (int nb = s + wid * 4; nb < e; nb += 16) {     // 4 waves x 4 slots
    const int n = nb + slot;
    float fv[8], d;
    if (n < e) {
      half8 hv = *(const half8*)(g_fb + (size_t)n * DIM + c * 8);
      d = 0.f;
#pragma unroll
      for (int j = 0; j < 8; ++j) { fv[j] = (float)hv[j]; d += fv[j] * w2r[j]; }
    } else {
      d = -1.0e30f;                                  // poison: slot inactive
#pragma unroll
      for (int j = 0; j < 8; ++j) fv[j] = 0.f;
    }
#pragma unroll
    for (int o = 1; o < 16; o <<= 1) d += __shfl_xor(d, o, 64);
    float m4 = fmaxf(d, __shfl_xor(d, 16, 64));
    m4 = fmaxf(m4, __shfl_xor(m4, 32, 64));
    float mnew = fmaxf(mrun, m4);
    float sc = __expf(mrun - mnew);
    float w = __expf(d - mnew);
    lsum = lsum * sc + w;
#pragma unroll
    for (int j = 0; j < 8; ++j) racc[j] = racc[j] * sc + w * fv[j];
    mrun = mnew;
  }
  float lt = lsum + __shfl_xor(lsum, 16, 64);
  lt += __shfl_xor(lt, 32, 64);
#pragma unroll
  for (int j = 0; j < 8; ++j) {
    racc[j] += __shfl_xor(racc[j], 16, 64);
    racc[j] += __shfl_xor(racc[j], 32, 64);
  }
  if (lid == 0) s_m[wid] = mrun;
  __syncthreads();
  float gmax = fmaxf(fmaxf(s_m[0], s_m[1]), fmaxf(s_m[2], s_m[3]));
  float scw = __expf(mrun - gmax);                   // wave-uniform
  if (lid < 16) {
    float4 lo = make_float4(racc[0] * scw, racc[1] * scw, racc[2] * scw, racc[3] * scw);
    float4 hi = make_float4(racc[4] * scw, racc[5] * scw, racc[6] * scw, racc[7] * scw);
    *(float4*)&s_s[wid][c * 8] = lo;
    *(float4*)&s_s[wid][c * 8 + 4] = hi;
  }
  if (lid == 0) s_l[wid] = lt * scw;
  __syncthreads();
  float total = s_l[0] + s_l[1] + s_l[2] + s_l[3];
  float inv = 1.f / (total + 1e-7f);
  if (t == 0) g_tp[g] = total * inv;
  if (t < 64) {
    int d0 = t * 2;
    float v0 = (s_s[0][d0] + s_s[1][d0] + s_s[2][d0] + s_s[3][d0]) * inv;
    float v1 = (s_s[0][d0 + 1] + s_s[1][d0 + 1] + s_s[2][d0 + 1] + s_s[3][d0 + 1]) * inv;
    ((unsigned*)g_sp)[(size_t)g * 64 + t] = (unsigned)f2h(v0) | ((unsigned)f2h(v1) << 16);
  }
}

// ---- GEMM: r = S' @ W_m^T + t'*b_m  (M=2048, N=512, K=128), 64x64 tiles ----
__global__ __launch_bounds__(256) void k_r(const void* __restrict__ bias,
                                           void* __restrict__ out, int wout) {
  __shared__ u16 As[64 * 64];
  __shared__ u16 Bs[64 * 64];
  const int t = threadIdx.x, lid = t & 63, w = t >> 6;
  const int m0 = blockIdx.x * 64, n0 = blockIdx.y * 64;
  const int rr = lid & 15, quad = lid >> 4;
  const int rsub = lid >> 3;
  const int cs = (lid & 7) ^ rsub;
  const int wm = (w >> 1) * 32, wn = (w & 1) * 32;
  f32x4 acc[2][2] = {};
  for (int kt = 0; kt < 2; ++kt) {
    const int k0 = kt * 64;
    GLD16(g_sp + (size_t)(m0 + w * 16 + rsub) * 128 + k0 + cs * 8, As + (w * 16) * 64);
    GLD16(g_sp + (size_t)(m0 + w * 16 + 8 + rsub) * 128 + k0 + cs * 8, As + (w * 16 + 8) * 64);
    GLD16(g_wm + (size_t)(n0 + w * 16 + rsub) * 128 + k0 + cs * 8, Bs + (w * 16) * 64);
    GLD16(g_wm + (size_t)(n0 + w * 16 + 8 + rsub) * 128 + k0 + cs * 8, Bs + (w * 16 + 8) * 64);
    __syncthreads();
#pragma unroll
    for (int kk = 0; kk < 2; ++kk) {
      const int qb = kk * 4 + quad;
      const int sw = (qb ^ (rr & 7)) << 3;
      half8 af[2], bfr[2];
#pragma unroll
      for (int i = 0; i < 2; ++i) af[i]  = *(const half8*)(As + (wm + i * 16 + rr) * 64 + sw);
#pragma unroll
      for (int j = 0; j < 2; ++j) bfr[j] = *(const half8*)(Bs + (wn + j * 16 + rr) * 64 + sw);
#pragma unroll
      for (int i = 0; i < 2; ++i)
#pragma unroll
        for (int j = 0; j < 2; ++j)
          acc[i][j] = __builtin_amdgcn_mfma_f32_16x16x32_f16(bfr[j], af[i], acc[i][j], 0, 0, 0);
    }
    __syncthreads();
  }
  const int isb = g_isbf16;
#pragma unroll
  for (int i = 0; i < 2; ++i) {
    const int row = m0 + wm + i * 16 + rr;           // graph
    const float tp = g_tp[row];
#pragma unroll
    for (int j = 0; j < 2; ++j) {
      const int c0 = n0 + wn + j * 16 + quad * 4;    // output col
      u16 h4[4]; float rv[4];
#pragma unroll
      for (int r = 0; r < 4; ++r) {
        rv[r] = acc[i][j][r] + tp * rdf(bias, c0 + r);
        h4[r] = f2h(rv[r]);
      }
      *(uint2*)(g_Acat + (size_t)row * 1024 + 512 + c0) =
          make_uint2((unsigned)h4[0] | ((unsigned)h4[1] << 16),
                     (unsigned)h4[2] | ((unsigned)h4[3] << 16));
      if (wout) {
        if (isb) {
          u16 b4[4];
#pragma unroll
          for (int r = 0; r < 4; ++r) b4[r] = f2bf(rv[r]);
          *(uint2*)((u16*)out + (size_t)row * 1024 + 512 + c0) =
              make_uint2((unsigned)b4[0] | ((unsigned)b4[1] << 16),
                         (unsigned)b4[2] | ((unsigned)b4[3] << 16));
        } else {
          *(f32x4*)((float*)out + (size_t)row * 1024 + 512 + c0) =
              *(f32x4*)rv;
        }
      }
    }
  }
}

extern "C" void kernel_launch(void* const* d_in, const int* in_sizes, int n_in,
                              void* d_out, int out_size, void* d_ws, size_t ws_size,
                              hipStream_t stream) {
  const void* features = d_in[0];
  const void* gidx     = d_in[1];
  const void* W_m      = d_in[2];
  const void* b_m      = d_in[3];
  const void* W_ih     = d_in[4];
  const void* W_hh     = d_in[5];
  const void* b_ih     = d_in[6];
  const void* b_hh     = d_in[7];

  k_detect<<<1, 256, 0, stream>>>(features, gidx);
  k_cvt_all<<<CVT_BLOCKS, 256, 0, stream>>>(features, W_m, W_ih, W_hh);
  k_offsets<<<N_NODES / 256, 256, 0, stream>>>(gidx);
  for (int loop = 0; loop < 3; ++loop) {
    const int wout = (loop == 2);
    if (loop > 0) k_gemm_gates<<<dim3(32, 32), 256, 0, stream>>>();
    k_lstm<<<NG / 4, 256, 0, stream>>>(b_ih, b_hh, d_out, wout, loop == 0);
    k_attn_s<<<NG, 256, 0, stream>>>();
    k_r<<<dim3(32, 8), 256, 0, stream>>>(b_m, d_out, wout);
  }
}

// Round 2
// 272.290 us; speedup vs baseline: 1.0782x; 1.0015x over previous
//
#include <hip/hip_runtime.h>

// ---- problem dims (fixed by setup_inputs) ----
#define N_NODES 131072
#define DIM     128
#define NG      2048
#define HD      512

typedef unsigned short u16;
typedef _Float16 half8 __attribute__((ext_vector_type(8)));
typedef float  f32x4  __attribute__((ext_vector_type(4)));

// ---- static device scratch (referenced ONLY from device code) ----
__device__ u16   g_fb[(size_t)N_NODES * DIM];     // features fp16 (33.5 MB)
__device__ u16   g_wm[(size_t)HD * DIM];          // W_m fp16 (rows j, cols d)
__device__ u16   g_wmT[(size_t)DIM * HD];         // W_m^T fp16 (rows d, cols j)
__device__ u16   g_wgf[(size_t)2048 * 640];       // [perm(Wih1+Whh) | perm(Wfold)] fp16
__device__ u16   g_wih2[(size_t)2048 * 512];      // perm(Wih[:,512:]) fp16
__device__ float g_bc[2048];                      // perm(b_ih+b_hh) fp32
__device__ float g_bf[2048];                      // perm(Wih2 @ b_m) fp32
__device__ float g_w2[(size_t)NG * DIM];          // w2 = h @ W_m, fp32 (1 MB)
__device__ float g_tp[NG];                        // t' = sum a_n
__device__ u16   g_Acat[(size_t)NG * 640];        // [h(512) | S'(128)] fp16
__device__ float g_c[(size_t)NG * HD];
__device__ int   g_start[NG + 1];
__device__ int   g_isbf16;
__device__ int   g_idx64;

__device__ __forceinline__ float bf2f(u16 u) {
  unsigned v = ((unsigned)u) << 16;
  float f; __builtin_memcpy(&f, &v, 4); return f;
}
__device__ __forceinline__ u16 f2bf(float f) {
  unsigned u; __builtin_memcpy(&u, &f, 4);
  u += 0x7FFFu + ((u >> 16) & 1u);
  return (u16)(u >> 16);
}
__device__ __forceinline__ u16 f2h(float f) {
  _Float16 h = (_Float16)f; u16 u; __builtin_memcpy(&u, &h, 2); return u;
}
__device__ __forceinline__ float rdf(const void* p, int i) {
  return g_isbf16 ? bf2f(((const u16*)p)[i]) : ((const float*)p)[i];
}

#define GLD16(gp, lp) __builtin_amdgcn_global_load_lds(                          \
    (const __attribute__((address_space(1))) void*)(gp),                         \
    (__attribute__((address_space(3))) void*)(lp), 16, 0, 0)

// ---- dtype detection ----
__global__ void k_detect(const void* feat, const void* gi) {
  __shared__ int cnt;
  if (threadIdx.x == 0) cnt = 0;
  __syncthreads();
  u16 u = ((const u16*)feat)[threadIdx.x];
  float v = bf2f(u);
  float a = fabsf(v);
  int ok = (v == v) && a >= 1e-6f && a <= 1e6f;
  atomicAdd(&cnt, ok);
  __syncthreads();
  if (threadIdx.x == 0) {
    g_isbf16 = (cnt >= 230);
    g_idx64 = (((const int*)gi)[N_NODES - 1] == 0);
  }
}

// ---- conversions (pair-indexed) ----
// gate-row permutation: permuted row n = 4*j + q  <->  orig row q*512 + j
#define NFP ((size_t)N_NODES * DIM / 2)
#define NWP ((size_t)HD * DIM / 2)
#define NWT ((size_t)DIM * HD / 2)
#define NW1 ((size_t)2048 * 512 / 2)
#define NW2 ((size_t)2048 * 512 / 2)
__global__ __launch_bounds__(256) void k_cvt_all(const void* f, const void* wm,
                                                 const void* wih, const void* whh) {
  const int isb = g_isbf16;
  size_t i = (size_t)blockIdx.x * 256 + threadIdx.x;
  if (i < NFP + NWP) {
    const void* src = (i < NFP) ? f : wm;
    u16* dst = (i < NFP) ? g_fb : g_wm;
    size_t off = (i < NFP) ? i : i - NFP;
    float v0, v1;
    if (isb) {
      unsigned pr = ((const unsigned*)src)[off];
      v0 = bf2f((u16)pr); v1 = bf2f((u16)(pr >> 16));
    } else {
      float2 v = ((const float2*)src)[off];
      v0 = v.x; v1 = v.y;
    }
    ((unsigned*)dst)[off] = (unsigned)f2h(v0) | ((unsigned)f2h(v1) << 16);
  } else if (i < NFP + NWP + NWT) {
    size_t p = i - NFP - NWP;
    int d = (int)(p >> 8), j = (int)(p & 255) * 2;   // wmT[d][j], wmT[d][j+1]
    float v0 = rdf(wm, j * DIM + d);
    float v1 = rdf(wm, (j + 1) * DIM + d);
    ((unsigned*)g_wmT)[(size_t)d * 256 + (j >> 1)] =
        (unsigned)f2h(v0) | ((unsigned)f2h(v1) << 16);
  } else if (i < NFP + NWP + NWT + NW1) {
    size_t p = i - NFP - NWP - NWT;
    int n = (int)(p >> 8), kp = (int)(p & 255), k = kp * 2;
    int orig = (n & 3) * 512 + (n >> 2);
    float v0 = rdf(wih, orig * 1024 + k)     + rdf(whh, orig * 512 + k);
    float v1 = rdf(wih, orig * 1024 + k + 1) + rdf(whh, orig * 512 + k + 1);
    ((unsigned*)g_wgf)[(size_t)n * 320 + kp] =
        (unsigned)f2h(v0) | ((unsigned)f2h(v1) << 16);
  } else if (i < NFP + NWP + NWT + NW1 + NW2) {
    size_t p = i - NFP - NWP - NWT - NW1;
    int n = (int)(p >> 8), kp = (int)(p & 255), k = kp * 2;
    int orig = (n & 3) * 512 + (n >> 2);
    float v0 = rdf(wih, orig * 1024 + 512 + k);
    float v1 = rdf(wih, orig * 1024 + 512 + k + 1);
    ((unsigned*)g_wih2)[(size_t)n * 256 + kp] =
        (unsigned)f2h(v0) | ((unsigned)f2h(v1) << 16);
  }
}
#define CVT_BLOCKS ((int)((NFP + NWP + NWT + NW1 + NW2 + 255) / 256))

// ---- permuted combined bias + bfold = perm(Wih2 @ b_m) ----
__global__ __launch_bounds__(256) void k_prep(const void* b_ih, const void* b_hh,
                                              const void* b_m) {
  const int n = blockIdx.x * 256 + threadIdx.x;    // grid 8
  const int orig = (n & 3) * 512 + (n >> 2);
  g_bc[n] = rdf(b_ih, orig) + rdf(b_hh, orig);
  float s = 0.f;
  for (int jb = 0; jb < 64; ++jb) {
    half8 wv = *(const half8*)(g_wih2 + (size_t)n * 512 + jb * 8);
#pragma unroll
    for (int d = 0; d < 8; ++d) s += (float)wv[d] * rdf(b_m, jb * 8 + d);
  }
  g_bf[n] = s;
}

// ---- per-graph start offsets from sorted graph_index ----
__global__ void k_offsets(const void* giv) {
  int n = blockIdx.x * 256 + threadIdx.x;
  if (n >= N_NODES) return;
  const int idx64 = g_idx64;
  int g = idx64 ? (int)((const long long*)giv)[n] : ((const int*)giv)[n];
  if (n == 0) {
    for (int x = 0; x <= g; ++x) g_start[x] = 0;
  } else {
    int gp = idx64 ? (int)((const long long*)giv)[n - 1] : ((const int*)giv)[n - 1];
    for (int x = gp + 1; x <= g; ++x) g_start[x] = n;
  }
  if (n == N_NODES - 1) {
    for (int x = g + 1; x <= NG; ++x) g_start[x] = N_NODES;
  }
}

// ---- GEMM M=2048,N=128,K=512 shared by w2 (mode 0) and Wfold (mode 1).
// mode 0: A = Acat h-half (stride 640), out fp32 g_w2.
// mode 1: A = g_wih2 (stride 512),     out fp16 -> g_wgf cols 512..639. ----
__global__ __launch_bounds__(256) void k_nk128(int mode) {
  __shared__ u16 As[64 * 64];
  __shared__ u16 Bs[64 * 64];
  const int t = threadIdx.x, lid = t & 63, w = t >> 6;
  const int m0 = blockIdx.x * 64, n0 = blockIdx.y * 64;
  const int rr = lid & 15, quad = lid >> 4;
  const int rsub = lid >> 3;
  const int cs = (lid & 7) ^ rsub;
  const int wm = (w >> 1) * 32, wn = (w & 1) * 32;
  const u16* Ap = mode ? g_wih2 : g_Acat;
  const int astr = mode ? 512 : 640;
  f32x4 acc[2][2] = {};
  for (int kt = 0; kt < 8; ++kt) {
    const int k0 = kt * 64;
    GLD16(Ap + (size_t)(m0 + w * 16 + rsub) * astr + k0 + cs * 8, As + (w * 16) * 64);
    GLD16(Ap + (size_t)(m0 + w * 16 + 8 + rsub) * astr + k0 + cs * 8, As + (w * 16 + 8) * 64);
    GLD16(g_wmT + (size_t)(n0 + w * 16 + rsub) * 512 + k0 + cs * 8, Bs + (w * 16) * 64);
    GLD16(g_wmT + (size_t)(n0 + w * 16 + 8 + rsub) * 512 + k0 + cs * 8, Bs + (w * 16 + 8) * 64);
    __syncthreads();
#pragma unroll
    for (int kk = 0; kk < 2; ++kk) {
      const int qb = kk * 4 + quad;
      const int sw = (qb ^ (rr & 7)) << 3;
      half8 af[2], bfr[2];
#pragma unroll
      for (int i = 0; i < 2; ++i) af[i]  = *(const half8*)(As + (wm + i * 16 + rr) * 64 + sw);
#pragma unroll
      for (int j = 0; j < 2; ++j) bfr[j] = *(const half8*)(Bs + (wn + j * 16 + rr) * 64 + sw);
#pragma unroll
      for (int i = 0; i < 2; ++i)
#pragma unroll
        for (int j = 0; j < 2; ++j)
          acc[i][j] = __builtin_amdgcn_mfma_f32_16x16x32_f16(bfr[j], af[i], acc[i][j], 0, 0, 0);
    }
    __syncthreads();
  }
#pragma unroll
  for (int i = 0; i < 2; ++i)
#pragma unroll
    for (int j = 0; j < 2; ++j) {
      const int row = m0 + wm + i * 16 + rr;
      const int c0 = n0 + wn + j * 16 + quad * 4;
      if (mode) {
        u16 h4[4];
#pragma unroll
        for (int r = 0; r < 4; ++r) h4[r] = f2h(acc[i][j][r]);
        *(uint2*)(g_wgf + (size_t)row * 640 + 512 + c0) =
            make_uint2((unsigned)h4[0] | ((unsigned)h4[1] << 16),
                       (unsigned)h4[2] | ((unsigned)h4[3] << 16));
      } else {
        *(f32x4*)(g_w2 + (size_t)row * 128 + c0) = acc[i][j];
      }
    }
}

// ---- GEMM gates (K=640, permuted cols) + fused LSTM epilogue.
// gates[g][4j+q] = h.Wg1 + S'.Wfold ; + bc + t'*bf in epilogue; then LSTM. ----
__global__ __launch_bounds__(256) void k_gemm_fused(void* __restrict__ out, int wout) {
  __shared__ u16 As[2][64 * 64];
  __shared__ u16 Bs[2][64 * 64];
  const int t = threadIdx.x, lid = t & 63, w = t >> 6;
  const int m0 = blockIdx.x * 64, n0 = blockIdx.y * 64;
  const int rr = lid & 15, quad = lid >> 4;
  const int rsub = lid >> 3;
  const int cs = (lid & 7) ^ rsub;
  const int wm = (w >> 1) * 32, wn = (w & 1) * 32;
  f32x4 acc[2][2] = {};
  for (int kt2 = 0; kt2 < 5; ++kt2) {
#pragma unroll
    for (int b = 0; b < 2; ++b) {
      const int k0 = (kt2 * 2 + b) * 64;
      GLD16(g_Acat + (size_t)(m0 + w * 16 + rsub) * 640 + k0 + cs * 8, As[b] + (w * 16) * 64);
      GLD16(g_Acat + (size_t)(m0 + w * 16 + 8 + rsub) * 640 + k0 + cs * 8, As[b] + (w * 16 + 8) * 64);
      GLD16(g_wgf  + (size_t)(n0 + w * 16 + rsub) * 640 + k0 + cs * 8, Bs[b] + (w * 16) * 64);
      GLD16(g_wgf  + (size_t)(n0 + w * 16 + 8 + rsub) * 640 + k0 + cs * 8, Bs[b] + (w * 16 + 8) * 64);
    }
    __syncthreads();
#pragma unroll
    for (int b = 0; b < 2; ++b)
#pragma unroll
      for (int kk = 0; kk < 2; ++kk) {
        const int qb = kk * 4 + quad;
        const int sw = (qb ^ (rr & 7)) << 3;
        half8 af[2], bfr[2];
#pragma unroll
        for (int i = 0; i < 2; ++i) af[i]  = *(const half8*)(As[b] + (wm + i * 16 + rr) * 64 + sw);
#pragma unroll
        for (int j = 0; j < 2; ++j) bfr[j] = *(const half8*)(Bs[b] + (wn + j * 16 + rr) * 64 + sw);
#pragma unroll
        for (int i = 0; i < 2; ++i)
#pragma unroll
          for (int j = 0; j < 2; ++j)
            acc[i][j] = __builtin_amdgcn_mfma_f32_16x16x32_f16(bfr[j], af[i], acc[i][j], 0, 0, 0);
      }
    __syncthreads();
  }
  const int isb = g_isbf16;
#pragma unroll
  for (int i = 0; i < 2; ++i) {
    const int row = m0 + wm + i * 16 + rr;           // graph
    const float tp = g_tp[row];
#pragma unroll
    for (int j = 0; j < 2; ++j) {
      const int c0 = n0 + wn + j * 16 + quad * 4;    // permuted gate col, %4==0
      const int jj = c0 >> 2;                        // hidden index
      float4 bc = *(const float4*)(g_bc + c0);
      float4 bf = *(const float4*)(g_bf + c0);
      float xi = acc[i][j][0] + bc.x + tp * bf.x;
      float xf = acc[i][j][1] + bc.y + tp * bf.y;
      float xg = acc[i][j][2] + bc.z + tp * bf.z;
      float xo = acc[i][j][3] + bc.w + tp * bf.w;
      float si = 1.f / (1.f + __expf(-xi));
      float sf = 1.f / (1.f + __expf(-xf));
      float tg = tanhf(xg);
      float so = 1.f / (1.f + __expf(-xo));
      float cn = sf * g_c[(size_t)row * 512 + jj] + si * tg;
      float hn = so * tanhf(cn);
      g_c[(size_t)row * 512 + jj] = cn;
      g_Acat[(size_t)row * 640 + jj] = f2h(hn);
      if (wout) {
        if (isb) ((u16*)out)[(size_t)row * 1024 + jj] = f2bf(hn);
        else     ((float*)out)[(size_t)row * 1024 + jj] = hn;
      }
    }
  }
}

// ---- loop-0 LSTM (gates = bias only, c_prev = 0) + fused w2 = h @ W_m.
// One block = 4 graphs. Grid NG/4 = 512. ----
__global__ __launch_bounds__(256) void k_lstm0(const void* __restrict__ b_ih,
                                               const void* __restrict__ b_hh) {
  __shared__ float s_hf[4][512];
  __shared__ float s_red[4][4][128];
  const int t = threadIdx.x;
  const int g0 = blockIdx.x * 4;
#pragma unroll
  for (int k = 0; k < 8; ++k) {
    const int idx = k * 256 + t;
    const int gg = idx >> 9, j = idx & 511;
    const int g = g0 + gg;
    float xi = rdf(b_ih, j)        + rdf(b_hh, j);
    float xg = rdf(b_ih, j + 1024) + rdf(b_hh, j + 1024);
    float xo = rdf(b_ih, j + 1536) + rdf(b_hh, j + 1536);
    float si = 1.f / (1.f + __expf(-xi));
    float tg = tanhf(xg);
    float so = 1.f / (1.f + __expf(-xo));
    float cn = si * tg;
    float hn = so * tanhf(cn);
    g_c[(size_t)g * 512 + j] = cn;
    g_Acat[(size_t)g * 640 + j] = f2h(hn);
    s_hf[gg][j] = hn;
  }
  __syncthreads();
  const int dg = t & 15, jg = t >> 4;
  float acc[4][8] = {};
  for (int jj = 0; jj < 32; ++jj) {
    const int j = jg * 32 + jj;
    half8 wv = *(const half8*)(g_wm + (size_t)j * 128 + dg * 8);
    float wf[8];
#pragma unroll
    for (int d = 0; d < 8; ++d) wf[d] = (float)wv[d];
#pragma unroll
    for (int g = 0; g < 4; ++g) {
      const float hv = s_hf[g][j];
#pragma unroll
      for (int d = 0; d < 8; ++d) acc[g][d] += hv * wf[d];
    }
  }
#pragma unroll
  for (int g = 0; g < 4; ++g)
#pragma unroll
    for (int d = 0; d < 8; ++d) {
      acc[g][d] += __shfl_xor(acc[g][d], 16, 64);
      acc[g][d] += __shfl_xor(acc[g][d], 32, 64);
    }
  const int w = t >> 6;
  if ((t & 63) < 16) {
#pragma unroll
    for (int g = 0; g < 4; ++g) {
      *(f32x4*)&s_red[w][g][dg * 8]     = *(f32x4*)&acc[g][0];
      *(f32x4*)&s_red[w][g][dg * 8 + 4] = *(f32x4*)&acc[g][4];
    }
  }
  __syncthreads();
  {
    const int g = t >> 6, d2 = (t & 63) * 2;
#pragma unroll
    for (int p = 0; p < 2; ++p) {
      const int d = d2 + p;
      g_w2[(size_t)(g0 + g) * 128 + d] =
          s_red[0][g][d] + s_red[1][g][d] + s_red[2][g][d] + s_red[3][g][d];
    }
  }
}

// ---- attention scores+softmax+weighted feature sum. One block per graph.
// Writes S' = sum(a_n f_n) fp16 into Acat cols 512..639, t' into g_tp. ----
__global__ __launch_bounds__(256) void k_attn_s() {
  const int g = blockIdx.x;
  const int t = threadIdx.x, lid = t & 63, wid = t >> 6;
  const int c = lid & 15;                            // 8-col chunk index
  const int slot = lid >> 4;                         // node slot 0..3
  __shared__ float s_m[4], s_l[4];
  __shared__ float s_s[4][DIM];
  const int s = g_start[g], e = g_start[g + 1];
  float w2r[8];
  *(float4*)(w2r)     = *(const float4*)(g_w2 + (size_t)g * DIM + c * 8);
  *(float4*)(w2r + 4) = *(const float4*)(g_w2 + (size_t)g * DIM + c * 8 + 4);
  float mrun = -3.0e38f, lsum = 0.f;
  float racc[8] = {0.f, 0.f, 0.f, 0.f, 0.f, 0.f, 0.f, 0.f};
  for (int nb = s + wid * 4; nb < e; nb += 16) {     // 4 waves x 4 slots
    const int n = nb + slot;
    float fv[8], d;
    if (n < e) {
      half8 hv = *(const half8*)(g_fb + (size_t)n * DIM + c * 8);
      d = 0.f;
#pragma unroll
      for (int j = 0; j < 8; ++j) { fv[j] = (float)hv[j]; d += fv[j] * w2r[j]; }
    } else {
      d = -1.0e30f;                                  // poison: slot inactive
#pragma unroll
      for (int j = 0; j < 8; ++j) fv[j] = 0.f;
    }
#pragma unroll
    for (int o = 1; o < 16; o <<= 1) d += __shfl_xor(d, o, 64);
    float m4 = fmaxf(d, __shfl_xor(d, 16, 64));
    m4 = fmaxf(m4, __shfl_xor(m4, 32, 64));
    float mnew = fmaxf(mrun, m4);
    float sc = __expf(mrun - mnew);
    float w = __expf(d - mnew);
    lsum = lsum * sc + w;
#pragma unroll
    for (int j = 0; j < 8; ++j) racc[j] = racc[j] * sc + w * fv[j];
    mrun = mnew;
  }
  float lt = lsum + __shfl_xor(lsum, 16, 64);
  lt += __shfl_xor(lt, 32, 64);
#pragma unroll
  for (int j = 0; j < 8; ++j) {
    racc[j] += __shfl_xor(racc[j], 16, 64);
    racc[j] += __shfl_xor(racc[j], 32, 64);
  }
  if (lid == 0) s_m[wid] = mrun;
  __syncthreads();
  float gmax = fmaxf(fmaxf(s_m[0], s_m[1]), fmaxf(s_m[2], s_m[3]));
  float scw = __expf(mrun - gmax);                   // wave-uniform
  if (lid < 16) {
    float4 lo = make_float4(racc[0] * scw, racc[1] * scw, racc[2] * scw, racc[3] * scw);
    float4 hi = make_float4(racc[4] * scw, racc[5] * scw, racc[6] * scw, racc[7] * scw);
    *(float4*)&s_s[wid][c * 8] = lo;
    *(float4*)&s_s[wid][c * 8 + 4] = hi;
  }
  if (lid == 0) s_l[wid] = lt * scw;
  __syncthreads();
  float total = s_l[0] + s_l[1] + s_l[2] + s_l[3];
  float inv = 1.f / (total + 1e-7f);
  if (t == 0) g_tp[g] = total * inv;
  if (t < 64) {
    int d0 = t * 2;
    float v0 = (s_s[0][d0] + s_s[1][d0] + s_s[2][d0] + s_s[3][d0]) * inv;
    float v1 = (s_s[0][d0 + 1] + s_s[1][d0 + 1] + s_s[2][d0 + 1] + s_s[3][d0 + 1]) * inv;
    ((unsigned*)g_Acat)[(size_t)g * 320 + 256 + t] =
        (unsigned)f2h(v0) | ((unsigned)f2h(v1) << 16);
  }
}

// ---- final r = S' @ W_m^T + t'*b_m -> out cols 512..1023 (loop 2 only) ----
__global__ __launch_bounds__(256) void k_r(const void* __restrict__ bias,
                                           void* __restrict__ out) {
  __shared__ u16 As[64 * 64];
  __shared__ u16 Bs[64 * 64];
  const int t = threadIdx.x, lid = t & 63, w = t >> 6;
  const int m0 = blockIdx.x * 64, n0 = blockIdx.y * 64;
  const int rr = lid & 15, quad = lid >> 4;
  const int rsub = lid >> 3;
  const int cs = (lid & 7) ^ rsub;
  const int wm = (w >> 1) * 32, wn = (w & 1) * 32;
  f32x4 acc[2][2] = {};
  for (int kt = 0; kt < 2; ++kt) {
    const int k0 = kt * 64;
    GLD16(g_Acat + (size_t)(m0 + w * 16 + rsub) * 640 + 512 + k0 + cs * 8, As + (w * 16) * 64);
    GLD16(g_Acat + (size_t)(m0 + w * 16 + 8 + rsub) * 640 + 512 + k0 + cs * 8, As + (w * 16 + 8) * 64);
    GLD16(g_wm + (size_t)(n0 + w * 16 + rsub) * 128 + k0 + cs * 8, Bs + (w * 16) * 64);
    GLD16(g_wm + (size_t)(n0 + w * 16 + 8 + rsub) * 128 + k0 + cs * 8, Bs + (w * 16 + 8) * 64);
    __syncthreads();
#pragma unroll
    for (int kk = 0; kk < 2; ++kk) {
      const int qb = kk * 4 + quad;
      const int sw = (qb ^ (rr & 7)) << 3;
      half8 af[2], bfr[2];
#pragma unroll
      for (int i = 0; i < 2; ++i) af[i]  = *(const half8*)(As + (wm + i * 16 + rr) * 64 + sw);
#pragma unroll
      for (int j = 0; j < 2; ++j) bfr[j] = *(const half8*)(Bs + (wn + j * 16 + rr) * 64 + sw);
#pragma unroll
      for (int i = 0; i < 2; ++i)
#pragma unroll
        for (int j = 0; j < 2; ++j)
          acc[i][j] = __builtin_amdgcn_mfma_f32_16x16x32_f16(bfr[j], af[i], acc[i][j], 0, 0, 0);
    }
    __syncthreads();
  }
  const int isb = g_isbf16;
#pragma unroll
  for (int i = 0; i < 2; ++i) {
    const int row = m0 + wm + i * 16 + rr;           // graph
    const float tp = g_tp[row];
#pragma unroll
    for (int j = 0; j < 2; ++j) {
      const int c0 = n0 + wn + j * 16 + quad * 4;    // output col
      float rv[4];
#pragma unroll
      for (int r = 0; r < 4; ++r) rv[r] = acc[i][j][r] + tp * rdf(bias, c0 + r);
      if (isb) {
        u16 b4[4];
#pragma unroll
        for (int r = 0; r < 4; ++r) b4[r] = f2bf(rv[r]);
        *(uint2*)((u16*)out + (size_t)row * 1024 + 512 + c0) =
            make_uint2((unsigned)b4[0] | ((unsigned)b4[1] << 16),
                       (unsigned)b4[2] | ((unsigned)b4[3] << 16));
      } else {
        *(f32x4*)((float*)out + (size_t)row * 1024 + 512 + c0) = *(f32x4*)rv;
      }
    }
  }
}

extern "C" void kernel_launch(void* const* d_in, const int* in_sizes, int n_in,
                              void* d_out, int out_size, void* d_ws, size_t ws_size,
                              hipStream_t stream) {
  const void* features = d_in[0];
  const void* gidx     = d_in[1];
  const void* W_m      = d_in[2];
  const void* b_m      = d_in[3];
  const void* W_ih     = d_in[4];
  const void* W_hh     = d_in[5];
  const void* b_ih     = d_in[6];
  const void* b_hh     = d_in[7];

  k_detect<<<1, 256, 0, stream>>>(features, gidx);
  k_cvt_all<<<CVT_BLOCKS, 256, 0, stream>>>(features, W_m, W_ih, W_hh);
  k_offsets<<<N_NODES / 256, 256, 0, stream>>>(gidx);
  k_prep<<<8, 256, 0, stream>>>(b_ih, b_hh, b_m);
  k_nk128<<<dim3(32, 2), 256, 0, stream>>>(1);       // Wfold -> g_wgf[:,512:640]
  // loop 0: gates = bias only
  k_lstm0<<<NG / 4, 256, 0, stream>>>(b_ih, b_hh);
  k_attn_s<<<NG, 256, 0, stream>>>();
  for (int loop = 1; loop < 3; ++loop) {
    const int wout = (loop == 2);
    k_gemm_fused<<<dim3(32, 32), 256, 0, stream>>>(d_out, wout);
    k_nk128<<<dim3(32, 2), 256, 0, stream>>>(0);     // w2 = h @ W_m
    k_attn_s<<<NG, 256, 0, stream>>>();
  }
  k_r<<<dim3(32, 8), 256, 0, stream>>>(b_m, d_out);
}